// Round 2
// baseline (4919.143 us; speedup 1.0000x reference)
//
#include <hip/hip_runtime.h>

#define V_ 96
#define T_ 16
#define E_ 64
#define H_ 4
#define K_ 16
#define L_ 4

__global__ void __launch_bounds__(64) bert_fwd(
    const int* __restrict__ data,
    const float* __restrict__ tok_emb, const float* __restrict__ pos_emb,
    const float* __restrict__ Wq, const float* __restrict__ Wk, const float* __restrict__ Wv,
    const float* __restrict__ Wo, const float* __restrict__ bo,
    const float* __restrict__ ln1g, const float* __restrict__ ln1b,
    const float* __restrict__ ln2g, const float* __restrict__ ln2b,
    const float* __restrict__ W1, const float* __restrict__ b1,
    const float* __restrict__ W2, const float* __restrict__ b2,
    const float* __restrict__ Wout, const float* __restrict__ bout,
    float* __restrict__ out)
{
  const int b = blockIdx.x;
  const int lane = threadIdx.x;
  const int t = lane >> 2;   // token 0..15
  const int g = lane & 3;    // quad slot 0..3

  // residual stream + scratch, fp32; padded strides to break bank aliasing
  __shared__ float xb[T_][E_ + 2];
  __shared__ float ob[T_][E_ + 2];
  __shared__ float qs[T_][K_ + 1];
  __shared__ float ks[T_][K_ + 1];
  __shared__ float vs[T_][K_ + 1];
  __shared__ float ps[T_][K_ + 1];

  // ---- embedding: x = tok_emb[data] + pos_emb ----
  {
    const int tok = data[b * T_ + t];
    const int c0 = g * 16;
    const float4* tp = (const float4*)(tok_emb + tok * E_ + c0);
    const float4* pp = (const float4*)(pos_emb + t * E_ + c0);
#pragma unroll
    for (int q = 0; q < 4; ++q) {
      float4 tv = tp[q];
      float4 pv = pp[q];
      xb[t][c0 + q * 4 + 0] = tv.x + pv.x;
      xb[t][c0 + q * 4 + 1] = tv.y + pv.y;
      xb[t][c0 + q * 4 + 2] = tv.z + pv.z;
      xb[t][c0 + q * 4 + 3] = tv.w + pv.w;
    }
  }
  __syncthreads();

  for (int l = 0; l < L_; ++l) {
    // ================= attention, one head at a time =================
    for (int h = 0; h < H_; ++h) {
      // q,k,v projections: lane computes token t, head-cols 4g..4g+3
      {
        const float* wq = Wq + ((l * H_ + h) * E_) * K_ + g * 4;
        const float* wk = Wk + ((l * H_ + h) * E_) * K_ + g * 4;
        const float* wv = Wv + ((l * H_ + h) * E_) * K_ + g * 4;
        float qa[4] = {0.f,0.f,0.f,0.f}, ka[4] = {0.f,0.f,0.f,0.f}, va[4] = {0.f,0.f,0.f,0.f};
#pragma unroll 8
        for (int e = 0; e < E_; ++e) {
          const float xv = xb[t][e];
          const float4 uq = *(const float4*)(wq + e * K_);
          const float4 uk = *(const float4*)(wk + e * K_);
          const float4 uv = *(const float4*)(wv + e * K_);
          qa[0] = fmaf(xv, uq.x, qa[0]);
          qa[1] = fmaf(xv, uq.y, qa[1]);
          qa[2] = fmaf(xv, uq.z, qa[2]);
          qa[3] = fmaf(xv, uq.w, qa[3]);
          ka[0] = fmaf(xv, uk.x, ka[0]);
          ka[1] = fmaf(xv, uk.y, ka[1]);
          ka[2] = fmaf(xv, uk.z, ka[2]);
          ka[3] = fmaf(xv, uk.w, ka[3]);
          va[0] = fmaf(xv, uv.x, va[0]);
          va[1] = fmaf(xv, uv.y, va[1]);
          va[2] = fmaf(xv, uv.z, va[2]);
          va[3] = fmaf(xv, uv.w, va[3]);
        }
#pragma unroll
        for (int j = 0; j < 4; ++j) {
          qs[t][g * 4 + j] = qa[j];
          ks[t][g * 4 + j] = ka[j];
          vs[t][g * 4 + j] = va[j];
        }
      }
      __syncthreads();

      // scores S[t][4g..4g+3], softmax over quad (covers s=0..15 of row t)
      {
        float sa[4] = {0.f,0.f,0.f,0.f};
#pragma unroll
        for (int k = 0; k < K_; ++k) {
          const float qv = qs[t][k];
          sa[0] = fmaf(qv, ks[g * 4 + 0][k], sa[0]);
          sa[1] = fmaf(qv, ks[g * 4 + 1][k], sa[1]);
          sa[2] = fmaf(qv, ks[g * 4 + 2][k], sa[2]);
          sa[3] = fmaf(qv, ks[g * 4 + 3][k], sa[3]);
        }
#pragma unroll
        for (int j = 0; j < 4; ++j) sa[j] *= 0.25f;  // 1/sqrt(16)
        float m = fmaxf(fmaxf(sa[0], sa[1]), fmaxf(sa[2], sa[3]));
        m = fmaxf(m, __shfl_xor(m, 1));
        m = fmaxf(m, __shfl_xor(m, 2));
        float ssum = 0.f;
#pragma unroll
        for (int j = 0; j < 4; ++j) { sa[j] = __expf(sa[j] - m); ssum += sa[j]; }
        ssum += __shfl_xor(ssum, 1);
        ssum += __shfl_xor(ssum, 2);
        const float inv = 1.0f / ssum;
#pragma unroll
        for (int j = 0; j < 4; ++j) ps[t][g * 4 + j] = sa[j] * inv;
      }
      __syncthreads();

      // o_h[t][c] = sum_s P[t][s] * v[s][c], into head-h columns of ob
      {
        float oa[4] = {0.f,0.f,0.f,0.f};
#pragma unroll
        for (int s = 0; s < T_; ++s) {
          const float pv = ps[t][s];
          oa[0] = fmaf(pv, vs[s][g * 4 + 0], oa[0]);
          oa[1] = fmaf(pv, vs[s][g * 4 + 1], oa[1]);
          oa[2] = fmaf(pv, vs[s][g * 4 + 2], oa[2]);
          oa[3] = fmaf(pv, vs[s][g * 4 + 3], oa[3]);
        }
#pragma unroll
        for (int j = 0; j < 4; ++j) ob[t][h * K_ + g * 4 + j] = oa[j];
      }
      __syncthreads();
    }

    // ================= x1 = LN1(x + o @ Wo + bo) =================
    {
      const int c0 = g * 16;
      float acc[16];
      {
        const float4* bp = (const float4*)(bo + l * E_ + c0);
#pragma unroll
        for (int q = 0; q < 4; ++q) {
          float4 bv = bp[q];
          acc[q * 4 + 0] = xb[t][c0 + q * 4 + 0] + bv.x;
          acc[q * 4 + 1] = xb[t][c0 + q * 4 + 1] + bv.y;
          acc[q * 4 + 2] = xb[t][c0 + q * 4 + 2] + bv.z;
          acc[q * 4 + 3] = xb[t][c0 + q * 4 + 3] + bv.w;
        }
      }
      const float* wo = Wo + (l * E_) * E_ + c0;
#pragma unroll 4
      for (int e = 0; e < E_; ++e) {
        const float ovv = ob[t][e];
        const float4* wp = (const float4*)(wo + e * E_);
#pragma unroll
        for (int q = 0; q < 4; ++q) {
          float4 wv4 = wp[q];
          acc[q * 4 + 0] = fmaf(ovv, wv4.x, acc[q * 4 + 0]);
          acc[q * 4 + 1] = fmaf(ovv, wv4.y, acc[q * 4 + 1]);
          acc[q * 4 + 2] = fmaf(ovv, wv4.z, acc[q * 4 + 2]);
          acc[q * 4 + 3] = fmaf(ovv, wv4.w, acc[q * 4 + 3]);
        }
      }
      float s = 0.f;
#pragma unroll
      for (int j = 0; j < 16; ++j) s += acc[j];
      s += __shfl_xor(s, 1); s += __shfl_xor(s, 2);
      const float mean = s * (1.0f / 64.0f);
      float vsum = 0.f;
#pragma unroll
      for (int j = 0; j < 16; ++j) { const float d = acc[j] - mean; vsum = fmaf(d, d, vsum); }
      vsum += __shfl_xor(vsum, 1); vsum += __shfl_xor(vsum, 2);
      const float r = rsqrtf(vsum * (1.0f / 64.0f) + 1e-5f);
      const float4* gp = (const float4*)(ln1g + l * E_ + c0);
      const float4* bp2 = (const float4*)(ln1b + l * E_ + c0);
#pragma unroll
      for (int q = 0; q < 4; ++q) {
        float4 gv = gp[q];
        float4 bv = bp2[q];
        xb[t][c0 + q * 4 + 0] = (acc[q * 4 + 0] - mean) * r * gv.x + bv.x;
        xb[t][c0 + q * 4 + 1] = (acc[q * 4 + 1] - mean) * r * gv.y + bv.y;
        xb[t][c0 + q * 4 + 2] = (acc[q * 4 + 2] - mean) * r * gv.z + bv.z;
        xb[t][c0 + q * 4 + 3] = (acc[q * 4 + 3] - mean) * r * gv.w + bv.w;
      }
    }
    __syncthreads();

    // ================= ff = relu(x1 @ W1 + b1) -> ob =================
    {
      const int c0 = g * 16;
      float acc[16];
      {
        const float4* bp = (const float4*)(b1 + l * E_ + c0);
#pragma unroll
        for (int q = 0; q < 4; ++q) {
          float4 bv = bp[q];
          acc[q * 4 + 0] = bv.x;
          acc[q * 4 + 1] = bv.y;
          acc[q * 4 + 2] = bv.z;
          acc[q * 4 + 3] = bv.w;
        }
      }
      const float* w1p = W1 + (l * E_) * E_ + c0;
#pragma unroll 4
      for (int e = 0; e < E_; ++e) {
        const float xv = xb[t][e];
        const float4* wp = (const float4*)(w1p + e * E_);
#pragma unroll
        for (int q = 0; q < 4; ++q) {
          float4 wv4 = wp[q];
          acc[q * 4 + 0] = fmaf(xv, wv4.x, acc[q * 4 + 0]);
          acc[q * 4 + 1] = fmaf(xv, wv4.y, acc[q * 4 + 1]);
          acc[q * 4 + 2] = fmaf(xv, wv4.z, acc[q * 4 + 2]);
          acc[q * 4 + 3] = fmaf(xv, wv4.w, acc[q * 4 + 3]);
        }
      }
#pragma unroll
      for (int j = 0; j < 16; ++j) ob[t][c0 + j] = fmaxf(acc[j], 0.f);
    }
    __syncthreads();

    // ================= x = LN2(x1 + ff @ W2 + b2) =================
    {
      const int c0 = g * 16;
      float acc[16];
      {
        const float4* bp = (const float4*)(b2 + l * E_ + c0);
#pragma unroll
        for (int q = 0; q < 4; ++q) {
          float4 bv = bp[q];
          acc[q * 4 + 0] = xb[t][c0 + q * 4 + 0] + bv.x;
          acc[q * 4 + 1] = xb[t][c0 + q * 4 + 1] + bv.y;
          acc[q * 4 + 2] = xb[t][c0 + q * 4 + 2] + bv.z;
          acc[q * 4 + 3] = xb[t][c0 + q * 4 + 3] + bv.w;
        }
      }
      const float* w2p = W2 + (l * E_) * E_ + c0;
#pragma unroll 4
      for (int e = 0; e < E_; ++e) {
        const float fv = ob[t][e];
        const float4* wp = (const float4*)(w2p + e * E_);
#pragma unroll
        for (int q = 0; q < 4; ++q) {
          float4 wv4 = wp[q];
          acc[q * 4 + 0] = fmaf(fv, wv4.x, acc[q * 4 + 0]);
          acc[q * 4 + 1] = fmaf(fv, wv4.y, acc[q * 4 + 1]);
          acc[q * 4 + 2] = fmaf(fv, wv4.z, acc[q * 4 + 2]);
          acc[q * 4 + 3] = fmaf(fv, wv4.w, acc[q * 4 + 3]);
        }
      }
      float s = 0.f;
#pragma unroll
      for (int j = 0; j < 16; ++j) s += acc[j];
      s += __shfl_xor(s, 1); s += __shfl_xor(s, 2);
      const float mean = s * (1.0f / 64.0f);
      float vsum = 0.f;
#pragma unroll
      for (int j = 0; j < 16; ++j) { const float d = acc[j] - mean; vsum = fmaf(d, d, vsum); }
      vsum += __shfl_xor(vsum, 1); vsum += __shfl_xor(vsum, 2);
      const float r = rsqrtf(vsum * (1.0f / 64.0f) + 1e-5f);
      const float4* gp = (const float4*)(ln2g + l * E_ + c0);
      const float4* bp2 = (const float4*)(ln2b + l * E_ + c0);
#pragma unroll
      for (int q = 0; q < 4; ++q) {
        float4 gv = gp[q];
        float4 bv = bp2[q];
        xb[t][c0 + q * 4 + 0] = (acc[q * 4 + 0] - mean) * r * gv.x + bv.x;
        xb[t][c0 + q * 4 + 1] = (acc[q * 4 + 1] - mean) * r * gv.y + bv.y;
        xb[t][c0 + q * 4 + 2] = (acc[q * 4 + 2] - mean) * r * gv.z + bv.z;
        xb[t][c0 + q * 4 + 3] = (acc[q * 4 + 3] - mean) * r * gv.w + bv.w;
      }
    }
    __syncthreads();
  }

  // ================= logits = x @ Wout + bout =================
  {
    const int c0 = g * 24;  // 96 cols / 4 lanes
    float acc[24];
    {
      const float4* bp = (const float4*)(bout + c0);
#pragma unroll
      for (int q = 0; q < 6; ++q) {
        float4 bv = bp[q];
        acc[q * 4 + 0] = bv.x;
        acc[q * 4 + 1] = bv.y;
        acc[q * 4 + 2] = bv.z;
        acc[q * 4 + 3] = bv.w;
      }
    }
#pragma unroll 2
    for (int e = 0; e < E_; ++e) {
      const float xv = xb[t][e];
      const float4* wp = (const float4*)(Wout + e * V_ + c0);
#pragma unroll
      for (int q = 0; q < 6; ++q) {
        float4 wv4 = wp[q];
        acc[q * 4 + 0] = fmaf(xv, wv4.x, acc[q * 4 + 0]);
        acc[q * 4 + 1] = fmaf(xv, wv4.y, acc[q * 4 + 1]);
        acc[q * 4 + 2] = fmaf(xv, wv4.z, acc[q * 4 + 2]);
        acc[q * 4 + 3] = fmaf(xv, wv4.w, acc[q * 4 + 3]);
      }
    }
    float4* ovp = (float4*)(out + (b * T_ + t) * V_ + c0);
#pragma unroll
    for (int q = 0; q < 6; ++q) {
      float4 rv;
      rv.x = acc[q * 4 + 0];
      rv.y = acc[q * 4 + 1];
      rv.z = acc[q * 4 + 2];
      rv.w = acc[q * 4 + 3];
      ovp[q] = rv;
    }
  }
}

extern "C" void kernel_launch(void* const* d_in, const int* in_sizes, int n_in,
                              void* d_out, int out_size, void* d_ws, size_t ws_size,
                              hipStream_t stream) {
  const int*   data    = (const int*)d_in[0];
  const float* tok_emb = (const float*)d_in[1];
  const float* pos_emb = (const float*)d_in[2];
  const float* Wq      = (const float*)d_in[3];
  const float* Wk      = (const float*)d_in[4];
  const float* Wv      = (const float*)d_in[5];
  const float* Wo      = (const float*)d_in[6];
  const float* bo      = (const float*)d_in[7];
  const float* ln1g    = (const float*)d_in[8];
  const float* ln1b    = (const float*)d_in[9];
  const float* ln2g    = (const float*)d_in[10];
  const float* ln2b    = (const float*)d_in[11];
  const float* W1      = (const float*)d_in[12];
  const float* b1      = (const float*)d_in[13];
  const float* W2      = (const float*)d_in[14];
  const float* b2      = (const float*)d_in[15];
  const float* Wout    = (const float*)d_in[16];
  const float* bout    = (const float*)d_in[17];
  float* out = (float*)d_out;

  const int B = in_sizes[0] / T_;  // 16384 sequences
  bert_fwd<<<B, 64, 0, stream>>>(data, tok_emb, pos_emb, Wq, Wk, Wv, Wo, bo,
                                 ln1g, ln1b, ln2g, ln2b, W1, b1, W2, b2,
                                 Wout, bout, out);
}

// Round 3
// 544.898 us; speedup vs baseline: 9.0276x; 9.0276x over previous
//
#include <hip/hip_runtime.h>

#define T_ 16
#define E_ 64
#define V_ 96
#define L_ 4

typedef unsigned int u32;
typedef __attribute__((ext_vector_type(8))) short bf16x8;
typedef __attribute__((ext_vector_type(4))) float f32x4;

#define MFMA(a, b, c) __builtin_amdgcn_mfma_f32_16x16x32_bf16(a, b, c, 0, 0, 0)

// ws layout (bf16/short elements): B-operand layout [n][k] per matrix
#define OFF_TQ 0
#define OFF_TK 16384
#define OFF_TV 32768
#define OFF_TWO 49152
#define OFF_TW1 65536
#define OFF_TW2 81920
#define OFF_TWOUT 98304
#define PREP_TOT 104448

__device__ __forceinline__ short f2b(float f) {  // fp32 -> bf16 RNE
  u32 u = __float_as_uint(f);
  u32 r = (u + 0x7fffu + ((u >> 16) & 1u)) >> 16;
  return (short)r;
}
__device__ __forceinline__ float b2f(short s) {
  return __uint_as_float(((u32)(unsigned short)s) << 16);
}
__device__ __forceinline__ u32 pack2(float a, float b) {
  return (u32)(unsigned short)f2b(a) | ((u32)(unsigned short)f2b(b) << 16);
}

// Convert fp32 weights -> bf16, transposed to [n][k] (k contiguous) so a
// B-fragment (lane n=lane&15, k=qq*8..+7) is one 16B load.
__global__ void __launch_bounds__(256) prep_weights(
    const float* __restrict__ Wq, const float* __restrict__ Wk,
    const float* __restrict__ Wv, const float* __restrict__ Wo,
    const float* __restrict__ W1, const float* __restrict__ W2,
    const float* __restrict__ Wout, short* __restrict__ wpo) {
  int id = blockIdx.x * 256 + threadIdx.x;
  if (id >= PREP_TOT) return;
  float v;
  if (id < OFF_TWO) {                       // TQ/TK/TV: n = h*16+kq, k = e
    int which = id >> 14;                   // 0=Q,1=K,2=V
    int r = id & 16383;
    int l = r >> 12, n = (r >> 6) & 63, e = r & 63;
    int h = n >> 4, kq = n & 15;
    const float* W = which == 0 ? Wq : (which == 1 ? Wk : Wv);
    v = W[((l * 4 + h) * 64 + e) * 16 + kq];
  } else if (id < OFF_TWOUT) {              // TWo/TW1/TW2: n = out col, k = e
    int id2 = id - OFF_TWO;
    int which = id2 >> 14;                  // 0=Wo,1=W1,2=W2
    int r = id2 & 16383;
    int l = r >> 12, n = (r >> 6) & 63, e = r & 63;
    const float* W = which == 0 ? Wo : (which == 1 ? W1 : W2);
    v = W[(l * 64 + e) * 64 + n];
  } else {                                  // TWout: n = vocab col, k = e
    int r = id - OFF_TWOUT;
    int n = r >> 6, e = r & 63;
    v = Wout[e * 96 + n];
  }
  wpo[id] = f2b(v);
}

// 256 threads = 4 waves; wave w handles sequence blockIdx.x*4+w entirely.
// No __syncthreads anywhere: every LDS buffer is private to one wave.
__global__ void bert_mfma(const int* __restrict__ data,
    const float* __restrict__ tok_emb, const float* __restrict__ pos_emb,
    const float* __restrict__ bo, const float* __restrict__ ln1g,
    const float* __restrict__ ln1b, const float* __restrict__ ln2g,
    const float* __restrict__ ln2b, const float* __restrict__ b1,
    const float* __restrict__ b2, const float* __restrict__ bout,
    const short* __restrict__ wp, float* __restrict__ out) {
  // per-wave scratch; strides 16B-aligned for ds_read_b128
  __shared__ __align__(16) short xsb[4][16][72];  // x (A-form, [t][e])
  __shared__ __align__(16) short obf[4][16][72];  // o / relu (A-form)
  __shared__ __align__(16) short qb[4][16][40];   // q [t][k], k 16..31 = 0
  __shared__ __align__(16) short kb[4][16][40];   // k [s][k]
  __shared__ __align__(16) short pb[4][16][40];   // P [t][s], s 16..31 = 0
  __shared__ __align__(16) short vb[4][16][40];   // v^T [kdim][s]

  const int w = threadIdx.x >> 6;
  const int lane = threadIdx.x & 63;
  const int m = lane & 15;   // A-row / B-col / C-col
  const int qq = lane >> 4;  // quad group: C rows qq*4..qq*4+3
  const int seq = blockIdx.x * 4 + w;

  short(*xs)[72] = xsb[w];
  short(*ob)[72] = obf[w];
  short(*qw)[40] = qb[w];
  short(*kw)[40] = kb[w];
  short(*pw)[40] = pb[w];
  short(*vw)[40] = vb[w];

  const f32x4 z4 = {0.f, 0.f, 0.f, 0.f};

  // zero attention buffers once (zero-pad region for K=32 MFMA stays 0)
  {
    float4 zz = make_float4(0.f, 0.f, 0.f, 0.f);
    float4* z;
    z = (float4*)&qw[0][0]; z[lane] = zz; if (lane < 16) z[64 + lane] = zz;
    z = (float4*)&kw[0][0]; z[lane] = zz; if (lane < 16) z[64 + lane] = zz;
    z = (float4*)&pw[0][0]; z[lane] = zz; if (lane < 16) z[64 + lane] = zz;
    z = (float4*)&vw[0][0]; z[lane] = zz; if (lane < 16) z[64 + lane] = zz;
  }

  // ---- embedding: x = tok_emb[data] + pos_emb -> xs (bf16, [t][e]) ----
  {
    const int t = lane >> 2;
    const int c0 = (lane & 3) * 16;
    const int tok = data[seq * T_ + t];
    const float4* tp = (const float4*)(tok_emb + tok * E_ + c0);
    const float4* pp = (const float4*)(pos_emb + t * E_ + c0);
    u32 buf[8];
#pragma unroll
    for (int q = 0; q < 4; ++q) {
      float4 a = tp[q], b = pp[q];
      buf[q * 2 + 0] = pack2(a.x + b.x, a.y + b.y);
      buf[q * 2 + 1] = pack2(a.z + b.z, a.w + b.w);
    }
    ((bf16x8*)&xs[t][c0])[0] = ((bf16x8*)buf)[0];
    ((bf16x8*)&xs[t][c0])[1] = ((bf16x8*)buf)[1];
  }

  // residual stream in C-layout registers: xres[tile][r] = x[qq*4+r][tile*16+m]
  float xres[4][4];
#pragma unroll
  for (int n = 0; n < 4; ++n)
#pragma unroll
    for (int r = 0; r < 4; ++r) xres[n][r] = b2f(xs[qq * 4 + r][n * 16 + m]);

  for (int l = 0; l < L_; ++l) {
    const short* TQ = wp + OFF_TQ + l * 4096;
    const short* TK = wp + OFF_TK + l * 4096;
    const short* TV = wp + OFF_TV + l * 4096;
    const short* TWO = wp + OFF_TWO + l * 4096;
    const short* TW1 = wp + OFF_TW1 + l * 4096;
    const short* TW2 = wp + OFF_TW2 + l * 4096;

    // A-fragments of x (reused for Q,K,V)
    bf16x8 ax0 = *(const bf16x8*)&xs[m][qq * 8];
    bf16x8 ax1 = *(const bf16x8*)&xs[m][32 + qq * 8];

    // ============ attention, head h = C n-tile h ============
    f32x4 ot[4];
#pragma unroll
    for (int h = 0; h < 4; ++h) {
      const int bn = (h * 16 + m) * 64 + qq * 8;
      bf16x8 bq0 = *(const bf16x8*)(TQ + bn);
      bf16x8 bq1 = *(const bf16x8*)(TQ + bn + 32);
      bf16x8 bk0 = *(const bf16x8*)(TK + bn);
      bf16x8 bk1 = *(const bf16x8*)(TK + bn + 32);
      bf16x8 bv0 = *(const bf16x8*)(TV + bn);
      bf16x8 bv1 = *(const bf16x8*)(TV + bn + 32);
      f32x4 qa = MFMA(ax0, bq0, z4); qa = MFMA(ax1, bq1, qa);
      f32x4 ka = MFMA(ax0, bk0, z4); ka = MFMA(ax1, bk1, ka);
      f32x4 va = MFMA(ax0, bv0, z4); va = MFMA(ax1, bv1, va);
      // q,k -> [t][kdim] / [s][kdim]; v -> v^T [kdim][s] (4 consecutive s)
#pragma unroll
      for (int r = 0; r < 4; ++r) {
        qw[qq * 4 + r][m] = f2b(qa[r]);
        kw[qq * 4 + r][m] = f2b(ka[r]);
      }
      *(uint2*)&vw[m][qq * 4] =
          make_uint2(pack2(va[0], va[1]), pack2(va[2], va[3]));
      // S = q k^T (K=32, upper half zeros)
      bf16x8 sA = *(const bf16x8*)&qw[m][qq * 8];
      bf16x8 sB = *(const bf16x8*)&kw[m][qq * 8];
      f32x4 sc = MFMA(sA, sB, z4);
      // softmax over s (16 lanes of this qq group), rows t = qq*4+r
#pragma unroll
      for (int r = 0; r < 4; ++r) {
        float sv = sc[r] * 0.25f;  // 1/sqrt(16)
        float mx = sv;
        mx = fmaxf(mx, __shfl_xor(mx, 1));
        mx = fmaxf(mx, __shfl_xor(mx, 2));
        mx = fmaxf(mx, __shfl_xor(mx, 4));
        mx = fmaxf(mx, __shfl_xor(mx, 8));
        float ev = __expf(sv - mx);
        float sm = ev;
        sm += __shfl_xor(sm, 1);
        sm += __shfl_xor(sm, 2);
        sm += __shfl_xor(sm, 4);
        sm += __shfl_xor(sm, 8);
        pw[qq * 4 + r][m] = f2b(ev * __builtin_amdgcn_rcpf(sm));
      }
      // O_h = P V  (K=32, s 16..31 zeros)
      bf16x8 pA = *(const bf16x8*)&pw[m][qq * 8];
      bf16x8 vB = *(const bf16x8*)&vw[m][qq * 8];
      ot[h] = MFMA(pA, vB, z4);
    }
    // concat heads -> ob (A-form)
#pragma unroll
    for (int h = 0; h < 4; ++h)
#pragma unroll
      for (int r = 0; r < 4; ++r) ob[qq * 4 + r][h * 16 + m] = f2b(ot[h][r]);

    // ============ x1 = LN1(x + o@Wo + bo) ============
    bf16x8 ao0 = *(const bf16x8*)&ob[m][qq * 8];
    bf16x8 ao1 = *(const bf16x8*)&ob[m][32 + qq * 8];
    f32x4 dt[4];
#pragma unroll
    for (int n = 0; n < 4; ++n) {
      const int bn = (n * 16 + m) * 64 + qq * 8;
      bf16x8 w0 = *(const bf16x8*)(TWO + bn);
      bf16x8 w1 = *(const bf16x8*)(TWO + bn + 32);
      dt[n] = MFMA(ao0, w0, z4); dt[n] = MFMA(ao1, w1, dt[n]);
    }
    float vals[4][4];
#pragma unroll
    for (int n = 0; n < 4; ++n) {
      float bcol = bo[l * E_ + n * 16 + m];
#pragma unroll
      for (int r = 0; r < 4; ++r) vals[n][r] = xres[n][r] + dt[n][r] + bcol;
    }
#pragma unroll
    for (int r = 0; r < 4; ++r) {
      float s = vals[0][r] + vals[1][r] + vals[2][r] + vals[3][r];
      s += __shfl_xor(s, 1); s += __shfl_xor(s, 2);
      s += __shfl_xor(s, 4); s += __shfl_xor(s, 8);
      float mean = s * (1.f / 64.f);
      float vv = 0.f;
#pragma unroll
      for (int n = 0; n < 4; ++n) { float d = vals[n][r] - mean; vv = fmaf(d, d, vv); }
      vv += __shfl_xor(vv, 1); vv += __shfl_xor(vv, 2);
      vv += __shfl_xor(vv, 4); vv += __shfl_xor(vv, 8);
      float rst = rsqrtf(vv * (1.f / 64.f) + 1e-5f);
#pragma unroll
      for (int n = 0; n < 4; ++n) vals[n][r] = (vals[n][r] - mean) * rst;
    }
#pragma unroll
    for (int n = 0; n < 4; ++n) {
      float gcol = ln1g[l * E_ + n * 16 + m];
      float bcol = ln1b[l * E_ + n * 16 + m];
#pragma unroll
      for (int r = 0; r < 4; ++r) {
        float xv = vals[n][r] * gcol + bcol;
        xres[n][r] = xv;
        xs[qq * 4 + r][n * 16 + m] = f2b(xv);
      }
    }

    // ============ h = relu(x1@W1 + b1) -> ob ============
    bf16x8 a10 = *(const bf16x8*)&xs[m][qq * 8];
    bf16x8 a11 = *(const bf16x8*)&xs[m][32 + qq * 8];
#pragma unroll
    for (int n = 0; n < 4; ++n) {
      const int bn = (n * 16 + m) * 64 + qq * 8;
      bf16x8 w0 = *(const bf16x8*)(TW1 + bn);
      bf16x8 w1 = *(const bf16x8*)(TW1 + bn + 32);
      f32x4 acc = MFMA(a10, w0, z4); acc = MFMA(a11, w1, acc);
      float bcol = b1[l * E_ + n * 16 + m];
#pragma unroll
      for (int r = 0; r < 4; ++r)
        ob[qq * 4 + r][n * 16 + m] = f2b(fmaxf(acc[r] + bcol, 0.f));
    }

    // ============ x = LN2(x1 + h@W2 + b2) ============
    bf16x8 a20 = *(const bf16x8*)&ob[m][qq * 8];
    bf16x8 a21 = *(const bf16x8*)&ob[m][32 + qq * 8];
#pragma unroll
    for (int n = 0; n < 4; ++n) {
      const int bn = (n * 16 + m) * 64 + qq * 8;
      bf16x8 w0 = *(const bf16x8*)(TW2 + bn);
      bf16x8 w1 = *(const bf16x8*)(TW2 + bn + 32);
      dt[n] = MFMA(a20, w0, z4); dt[n] = MFMA(a21, w1, dt[n]);
    }
#pragma unroll
    for (int n = 0; n < 4; ++n) {
      float bcol = b2[l * E_ + n * 16 + m];
#pragma unroll
      for (int r = 0; r < 4; ++r) vals[n][r] = xres[n][r] + dt[n][r] + bcol;
    }
#pragma unroll
    for (int r = 0; r < 4; ++r) {
      float s = vals[0][r] + vals[1][r] + vals[2][r] + vals[3][r];
      s += __shfl_xor(s, 1); s += __shfl_xor(s, 2);
      s += __shfl_xor(s, 4); s += __shfl_xor(s, 8);
      float mean = s * (1.f / 64.f);
      float vv = 0.f;
#pragma unroll
      for (int n = 0; n < 4; ++n) { float d = vals[n][r] - mean; vv = fmaf(d, d, vv); }
      vv += __shfl_xor(vv, 1); vv += __shfl_xor(vv, 2);
      vv += __shfl_xor(vv, 4); vv += __shfl_xor(vv, 8);
      float rst = rsqrtf(vv * (1.f / 64.f) + 1e-5f);
#pragma unroll
      for (int n = 0; n < 4; ++n) vals[n][r] = (vals[n][r] - mean) * rst;
    }
#pragma unroll
    for (int n = 0; n < 4; ++n) {
      float gcol = ln2g[l * E_ + n * 16 + m];
      float bcol = ln2b[l * E_ + n * 16 + m];
#pragma unroll
      for (int r = 0; r < 4; ++r) {
        float xv = vals[n][r] * gcol + bcol;
        xres[n][r] = xv;
        xs[qq * 4 + r][n * 16 + m] = f2b(xv);
      }
    }
  }

  // ============ logits = x @ Wout + bout (N=96 -> 6 tiles) ============
  {
    bf16x8 af0 = *(const bf16x8*)&xs[m][qq * 8];
    bf16x8 af1 = *(const bf16x8*)&xs[m][32 + qq * 8];
    const short* TWOUT = wp + OFF_TWOUT;
#pragma unroll
    for (int n = 0; n < 6; ++n) {
      const int bn = (n * 16 + m) * 64 + qq * 8;
      bf16x8 w0 = *(const bf16x8*)(TWOUT + bn);
      bf16x8 w1 = *(const bf16x8*)(TWOUT + bn + 32);
      f32x4 acc = MFMA(af0, w0, z4); acc = MFMA(af1, w1, acc);
      float bcol = bout[n * 16 + m];
#pragma unroll
      for (int r = 0; r < 4; ++r)
        out[(seq * T_ + qq * 4 + r) * V_ + n * 16 + m] = acc[r] + bcol;
    }
  }
}

extern "C" void kernel_launch(void* const* d_in, const int* in_sizes, int n_in,
                              void* d_out, int out_size, void* d_ws, size_t ws_size,
                              hipStream_t stream) {
  const int*   data    = (const int*)d_in[0];
  const float* tok_emb = (const float*)d_in[1];
  const float* pos_emb = (const float*)d_in[2];
  const float* Wq      = (const float*)d_in[3];
  const float* Wk      = (const float*)d_in[4];
  const float* Wv      = (const float*)d_in[5];
  const float* Wo      = (const float*)d_in[6];
  const float* bo      = (const float*)d_in[7];
  const float* ln1g    = (const float*)d_in[8];
  const float* ln1b    = (const float*)d_in[9];
  const float* ln2g    = (const float*)d_in[10];
  const float* ln2b    = (const float*)d_in[11];
  const float* W1      = (const float*)d_in[12];
  const float* b1      = (const float*)d_in[13];
  const float* W2      = (const float*)d_in[14];
  const float* b2      = (const float*)d_in[15];
  const float* Wout    = (const float*)d_in[16];
  const float* bout    = (const float*)d_in[17];
  float* out = (float*)d_out;
  short* wp = (short*)d_ws;  // needs 104448*2 = 208896 B of workspace

  prep_weights<<<(PREP_TOT + 255) / 256, 256, 0, stream>>>(
      Wq, Wk, Wv, Wo, W1, W2, Wout, wp);

  const int B = in_sizes[0] / T_;  // 16384 sequences, 4 per block
  bert_mfma<<<B / 4, 256, 0, stream>>>(data, tok_emb, pos_emb, bo, ln1g, ln1b,
                                       ln2g, ln2b, b1, b2, bout, wp, out);
}

// Round 4
// 519.252 us; speedup vs baseline: 9.4735x; 1.0494x over previous
//
#include <hip/hip_runtime.h>

#define T_ 16
#define E_ 64
#define V_ 96
#define L_ 4

typedef unsigned int u32;
typedef unsigned short u16;
typedef __attribute__((ext_vector_type(8))) short bf16x8;
typedef __attribute__((ext_vector_type(4))) float f32x4;

#define MFMA(a, b, c) __builtin_amdgcn_mfma_f32_16x16x32_bf16(a, b, c, 0, 0, 0)

// ws layout (bf16/short elements): B-operand layout [n][k] per matrix
#define OFF_TQ 0
#define OFF_TK 16384
#define OFF_TV 32768
#define OFF_TWO 49152
#define OFF_TW1 65536
#define OFF_TW2 81920
#define OFF_TWOUT 98304
#define PREP_TOT 104448

__device__ __forceinline__ short f2b_rne(float f) {  // fp32 -> bf16 RNE (prep only)
  u32 u = __float_as_uint(f);
  u32 r = (u + 0x7fffu + ((u >> 16) & 1u)) >> 16;
  return (short)r;
}
__device__ __forceinline__ float b2f(short s) {
  return __uint_as_float(((u32)(u16)s) << 16);
}
// round-half-up bf16 pack: low short = bf16(a), high short = bf16(b). 3 VALU.
__device__ __forceinline__ u32 pack2_ru(float a, float b) {
  return __builtin_amdgcn_perm(__float_as_uint(a) + 0x8000u,
                               __float_as_uint(b) + 0x8000u, 0x03020706u);
}

__global__ void __launch_bounds__(256) prep_weights(
    const float* __restrict__ Wq, const float* __restrict__ Wk,
    const float* __restrict__ Wv, const float* __restrict__ Wo,
    const float* __restrict__ W1, const float* __restrict__ W2,
    const float* __restrict__ Wout, short* __restrict__ wpo) {
  int id = blockIdx.x * 256 + threadIdx.x;
  if (id >= PREP_TOT) return;
  float v;
  if (id < OFF_TWO) {                       // TQ/TK/TV: n = h*16+kq, k = e
    int which = id >> 14;                   // 0=Q,1=K,2=V
    int r = id & 16383;
    int l = r >> 12, n = (r >> 6) & 63, e = r & 63;
    int h = n >> 4, kq = n & 15;
    const float* W = which == 0 ? Wq : (which == 1 ? Wk : Wv);
    v = W[((l * 4 + h) * 64 + e) * 16 + kq];
  } else if (id < OFF_TWOUT) {              // TWo/TW1/TW2: n = out col, k = e
    int id2 = id - OFF_TWO;
    int which = id2 >> 14;                  // 0=Wo,1=W1,2=W2
    int r = id2 & 16383;
    int l = r >> 12, n = (r >> 6) & 63, e = r & 63;
    const float* W = which == 0 ? Wo : (which == 1 ? W1 : W2);
    v = W[(l * 64 + e) * 64 + n];
  } else {                                  // TWout: n = vocab col, k = e
    int r = id - OFF_TWOUT;
    int n = r >> 6, e = r & 63;
    v = Wout[e * 96 + n];
  }
  wpo[id] = f2b_rne(v);
}

// LayerNorm over 64 cols held as 4 n-regs x 16 lanes (same qq group), rows r.
__device__ __forceinline__ void ln16(float vals[4][4]) {
#pragma unroll
  for (int r = 0; r < 4; ++r) {
    float s = vals[0][r] + vals[1][r] + vals[2][r] + vals[3][r];
    s += __shfl_xor(s, 1); s += __shfl_xor(s, 2);
    s += __shfl_xor(s, 4); s += __shfl_xor(s, 8);
    float mean = s * 0.015625f;
    float vv = 0.f;
#pragma unroll
    for (int n = 0; n < 4; ++n) { float d = vals[n][r] - mean; vv = fmaf(d, d, vv); }
    vv += __shfl_xor(vv, 1); vv += __shfl_xor(vv, 2);
    vv += __shfl_xor(vv, 4); vv += __shfl_xor(vv, 8);
    float rst = rsqrtf(vv * 0.015625f + 1e-5f);
#pragma unroll
    for (int n = 0; n < 4; ++n) vals[n][r] = (vals[n][r] - mean) * rst;
  }
}

// 256 threads = 4 waves; wave w handles sequence blockIdx.x*4+w. No
// __syncthreads: all LDS regions are wave-private. Three [16][72] arenas per
// wave with time-overlays: R0 = x(A-form)/vT, R1 = q_all/p_all, R2 = k_all/ob.
__global__ void __launch_bounds__(256, 4) bert_mfma(
    const int* __restrict__ data,
    const float* __restrict__ tok_emb, const float* __restrict__ pos_emb,
    const float* __restrict__ bo, const float* __restrict__ ln1g,
    const float* __restrict__ ln1b, const float* __restrict__ ln2g,
    const float* __restrict__ ln2b, const float* __restrict__ b1,
    const float* __restrict__ b2, const float* __restrict__ bout,
    const short* __restrict__ wp, float* __restrict__ out) {
  __shared__ __align__(16) short R0[4][16][72];
  __shared__ __align__(16) short R1[4][16][72];
  __shared__ __align__(16) short R2[4][16][72];

  const int w = threadIdx.x >> 6;
  const int lane = threadIdx.x & 63;
  const int m = lane & 15;   // A-row t / B-row / C-col
  const int qq = lane >> 4;  // k-chunk for frags; C rows qq*4+r
  const int seq = blockIdx.x * 4 + w;

  short(*xs)[72] = R0[w];  // x (rows=t, cols=e) then vT (rows=kd, cols=h*16+s)
  short(*qw)[72] = R1[w];  // q_all then p_all (rows=t, cols=h*16+kd|s)
  short(*kw)[72] = R2[w];  // k_all (rows=s) then ob (rows=t, cols=e)

  // zero cols 64..71 of R1: A-frag upper-K lanes (qq>=2) read here -> 0
  if (lane < 16) *(float4*)&R1[w][lane][64] = make_float4(0.f, 0.f, 0.f, 0.f);

  // ---- embedding: x = tok_emb[data] + pos_emb -> xs bf16 [t][e] ----
  {
    const int t = lane >> 2;
    const int c0 = (lane & 3) * 16;
    const int tok = data[seq * T_ + t];
    const float4* tp = (const float4*)(tok_emb + tok * E_ + c0);
    const float4* pp = (const float4*)(pos_emb + t * E_ + c0);
    u32 buf[8];
#pragma unroll
    for (int q = 0; q < 4; ++q) {
      float4 a = tp[q], b = pp[q];
      buf[q * 2 + 0] = pack2_ru(a.x + b.x, a.y + b.y);
      buf[q * 2 + 1] = pack2_ru(a.z + b.z, a.w + b.w);
    }
    ((bf16x8*)&xs[t][c0])[0] = ((bf16x8*)buf)[0];
    *(bf16x8*)&xs[t][c0 + 8] = ((bf16x8*)(buf + 4))[0];
  }

  // residual stream, C-layout regs: xres[n][r] = x[qq*4+r][n*16+m]
  float xres[4][4];
#pragma unroll
  for (int n = 0; n < 4; ++n)
#pragma unroll
    for (int r = 0; r < 4; ++r) xres[n][r] = b2f(xs[qq * 4 + r][n * 16 + m]);

  const short s1b = (short)0x3F80;
  const bf16x8 ones8 = {s1b, s1b, s1b, s1b, s1b, s1b, s1b, s1b};
  const f32x4 z4 = {0.f, 0.f, 0.f, 0.f};
  const int hselA = (qq < 2) ? 16 : 0;            // head stride for A-frag
  const int aoffA = (qq < 2) ? ((qq & 1) * 8) : 64;  // qq>=2 -> zero cols
  const int boff = (qq & 1) * 8;                  // B-frag k>=16 multiplied by A zeros

#pragma unroll 1
  for (int l = 0; l < L_; ++l) {
    const short* TQ = wp + OFF_TQ + l * 4096;
    const short* TK = wp + OFF_TK + l * 4096;
    const short* TV = wp + OFF_TV + l * 4096;
    const short* TWO = wp + OFF_TWO + l * 4096;
    const short* TW1 = wp + OFF_TW1 + l * 4096;
    const short* TW2 = wp + OFF_TW2 + l * 4096;

    // phase 1: x A-frags (before vT overwrites R0)
    bf16x8 ax0 = *(const bf16x8*)&xs[m][qq * 8];
    bf16x8 ax1 = *(const bf16x8*)&xs[m][32 + qq * 8];

    // phase 2: QKV, all heads (24 independent MFMAs)
#pragma unroll
    for (int h = 0; h < 4; ++h) {
      const int bn = (h * 16 + m) * 64 + qq * 8;
      bf16x8 bq0 = *(const bf16x8*)(TQ + bn), bq1 = *(const bf16x8*)(TQ + bn + 32);
      bf16x8 bk0 = *(const bf16x8*)(TK + bn), bk1 = *(const bf16x8*)(TK + bn + 32);
      bf16x8 bv0 = *(const bf16x8*)(TV + bn), bv1 = *(const bf16x8*)(TV + bn + 32);
      f32x4 qa = MFMA(ax0, bq0, z4); qa = MFMA(ax1, bq1, qa);
      f32x4 ka = MFMA(ax0, bk0, z4); ka = MFMA(ax1, bk1, ka);
      f32x4 va = MFMA(ax0, bv0, z4); va = MFMA(ax1, bv1, va);
      // q,k -> [t][h*16+kd], paired b32 stores (even lanes write col m,m+1)
#pragma unroll
      for (int r = 0; r < 4; ++r) {
        float qo = __shfl_xor(qa[r], 1);
        float ko = __shfl_xor(ka[r], 1);
        if (!(lane & 1)) {
          *(u32*)&qw[qq * 4 + r][h * 16 + m] = pack2_ru(qa[r], qo);
          *(u32*)&kw[qq * 4 + r][h * 16 + m] = pack2_ru(ka[r], ko);
        }
      }
      // vT[kd][h*16+t]: 4 consecutive t in-lane -> one b64
      *(uint2*)&xs[m][h * 16 + qq * 4] =
          make_uint2(pack2_ru(va[0], va[1]), pack2_ru(va[2], va[3]));
    }

    // phase 3: S_h = q k^T (4 independent MFMAs; A zero-cols give K 16..31 = 0)
    f32x4 sc[4];
#pragma unroll
    for (int h = 0; h < 4; ++h) {
      bf16x8 aq = *(const bf16x8*)&qw[m][h * hselA + aoffA];
      bf16x8 bk = *(const bf16x8*)&kw[m][h * 16 + boff];
      sc[h] = MFMA(aq, bk, z4);
    }

    // phase 4: p_un = exp(S/4) (no max-sub: |S| << 1), write over q region
#pragma unroll
    for (int h = 0; h < 4; ++h)
#pragma unroll
      for (int r = 0; r < 4; ++r) {
        float e = __expf(sc[h][r] * 0.25f);
        float eo = __shfl_xor(e, 1);
        if (!(lane & 1)) *(u32*)&qw[qq * 4 + r][h * 16 + m] = pack2_ru(e, eo);
      }

    // phase 5: O_h = p_un V, rowsum via ones-B MFMA (no shuffle reductions)
    f32x4 ot[4], rs[4];
#pragma unroll
    for (int h = 0; h < 4; ++h) {
      bf16x8 ap = *(const bf16x8*)&qw[m][h * hselA + aoffA];
      bf16x8 bv = *(const bf16x8*)&xs[m][h * 16 + boff];
      ot[h] = MFMA(ap, bv, z4);
      rs[h] = MFMA(ap, ones8, z4);
    }

    // phase 6: normalize + concat heads -> ob (over k region)
#pragma unroll
    for (int h = 0; h < 4; ++h)
#pragma unroll
      for (int r = 0; r < 4; ++r) {
        float o = ot[h][r] * __builtin_amdgcn_rcpf(rs[h][r]);
        float oo = __shfl_xor(o, 1);
        if (!(lane & 1)) *(u32*)&kw[qq * 4 + r][h * 16 + m] = pack2_ru(o, oo);
      }

    // phase 7: x1 = LN1(x + o@Wo + bo) -> xs (vT dead), xres
    {
      bf16x8 ao0 = *(const bf16x8*)&kw[m][qq * 8];
      bf16x8 ao1 = *(const bf16x8*)&kw[m][32 + qq * 8];
      f32x4 dt[4];
#pragma unroll
      for (int n = 0; n < 4; ++n) {
        const int bn = (n * 16 + m) * 64 + qq * 8;
        bf16x8 w0 = *(const bf16x8*)(TWO + bn), w1 = *(const bf16x8*)(TWO + bn + 32);
        f32x4 a = MFMA(ao0, w0, z4); dt[n] = MFMA(ao1, w1, a);
      }
      float vals[4][4];
#pragma unroll
      for (int n = 0; n < 4; ++n) {
        float bcol = bo[l * E_ + n * 16 + m];
#pragma unroll
        for (int r = 0; r < 4; ++r) vals[n][r] = xres[n][r] + dt[n][r] + bcol;
      }
      ln16(vals);
#pragma unroll
      for (int n = 0; n < 4; ++n) {
        float g = ln1g[l * E_ + n * 16 + m];
        float bb = ln1b[l * E_ + n * 16 + m];
#pragma unroll
        for (int r = 0; r < 4; ++r) {
          float xv = fmaf(vals[n][r], g, bb);
          xres[n][r] = xv;
          float xo = __shfl_xor(xv, 1);
          if (!(lane & 1)) *(u32*)&xs[qq * 4 + r][n * 16 + m] = pack2_ru(xv, xo);
        }
      }
    }

    // phase 8: h1 = relu(x1@W1 + b1) -> ob region
    {
      bf16x8 a10 = *(const bf16x8*)&xs[m][qq * 8];
      bf16x8 a11 = *(const bf16x8*)&xs[m][32 + qq * 8];
#pragma unroll
      for (int n = 0; n < 4; ++n) {
        const int bn = (n * 16 + m) * 64 + qq * 8;
        bf16x8 w0 = *(const bf16x8*)(TW1 + bn), w1 = *(const bf16x8*)(TW1 + bn + 32);
        f32x4 acc = MFMA(a10, w0, z4); acc = MFMA(a11, w1, acc);
        float bcol = b1[l * E_ + n * 16 + m];
#pragma unroll
        for (int r = 0; r < 4; ++r) {
          float hv = fmaxf(acc[r] + bcol, 0.f);
          float ho = __shfl_xor(hv, 1);
          if (!(lane & 1)) *(u32*)&kw[qq * 4 + r][n * 16 + m] = pack2_ru(hv, ho);
        }
      }
    }

    // phase 9: x = LN2(x1 + h1@W2 + b2) -> xs, xres
    {
      bf16x8 a20 = *(const bf16x8*)&kw[m][qq * 8];
      bf16x8 a21 = *(const bf16x8*)&kw[m][32 + qq * 8];
      f32x4 dt[4];
#pragma unroll
      for (int n = 0; n < 4; ++n) {
        const int bn = (n * 16 + m) * 64 + qq * 8;
        bf16x8 w0 = *(const bf16x8*)(TW2 + bn), w1 = *(const bf16x8*)(TW2 + bn + 32);
        f32x4 a = MFMA(a20, w0, z4); dt[n] = MFMA(a21, w1, a);
      }
      float vals[4][4];
#pragma unroll
      for (int n = 0; n < 4; ++n) {
        float bcol = b2[l * E_ + n * 16 + m];
#pragma unroll
        for (int r = 0; r < 4; ++r) vals[n][r] = xres[n][r] + dt[n][r] + bcol;
      }
      ln16(vals);
#pragma unroll
      for (int n = 0; n < 4; ++n) {
        float g = ln2g[l * E_ + n * 16 + m];
        float bb = ln2b[l * E_ + n * 16 + m];
#pragma unroll
        for (int r = 0; r < 4; ++r) {
          float xv = fmaf(vals[n][r], g, bb);
          xres[n][r] = xv;
          float xo = __shfl_xor(xv, 1);
          if (!(lane & 1)) *(u32*)&xs[qq * 4 + r][n * 16 + m] = pack2_ru(xv, xo);
        }
      }
    }
  }

  // epilogue: logits = x @ Wout + bout (6 n-tiles), fp32 coalesced stores
  {
    bf16x8 af0 = *(const bf16x8*)&xs[m][qq * 8];
    bf16x8 af1 = *(const bf16x8*)&xs[m][32 + qq * 8];
    const short* TWOUT = wp + OFF_TWOUT;
#pragma unroll
    for (int n = 0; n < 6; ++n) {
      const int bn = (n * 16 + m) * 64 + qq * 8;
      bf16x8 w0 = *(const bf16x8*)(TWOUT + bn), w1 = *(const bf16x8*)(TWOUT + bn + 32);
      f32x4 acc = MFMA(af0, w0, z4); acc = MFMA(af1, w1, acc);
      float bcol = bout[n * 16 + m];
#pragma unroll
      for (int r = 0; r < 4; ++r)
        out[(seq * T_ + qq * 4 + r) * V_ + n * 16 + m] = acc[r] + bcol;
    }
  }
}

extern "C" void kernel_launch(void* const* d_in, const int* in_sizes, int n_in,
                              void* d_out, int out_size, void* d_ws, size_t ws_size,
                              hipStream_t stream) {
  const int*   data    = (const int*)d_in[0];
  const float* tok_emb = (const float*)d_in[1];
  const float* pos_emb = (const float*)d_in[2];
  const float* Wq      = (const float*)d_in[3];
  const float* Wk      = (const float*)d_in[4];
  const float* Wv      = (const float*)d_in[5];
  const float* Wo      = (const float*)d_in[6];
  const float* bo      = (const float*)d_in[7];
  const float* ln1g    = (const float*)d_in[8];
  const float* ln1b    = (const float*)d_in[9];
  const float* ln2g    = (const float*)d_in[10];
  const float* ln2b    = (const float*)d_in[11];
  const float* W1      = (const float*)d_in[12];
  const float* b1      = (const float*)d_in[13];
  const float* W2      = (const float*)d_in[14];
  const float* b2      = (const float*)d_in[15];
  const float* Wout    = (const float*)d_in[16];
  const float* bout    = (const float*)d_in[17];
  float* out = (float*)d_out;
  short* wp = (short*)d_ws;  // 104448*2 = 208896 B of workspace

  prep_weights<<<(PREP_TOT + 255) / 256, 256, 0, stream>>>(
      Wq, Wk, Wv, Wo, W1, W2, Wout, wp);

  const int B = in_sizes[0] / T_;  // 16384 sequences, 4 per block
  bert_mfma<<<B / 4, 256, 0, stream>>>(data, tok_emb, pos_emb, bo, ln1g, ln1b,
                                       ln2g, ln2b, b1, b2, bout, wp, out);
}